// Round 8
// baseline (49811.551 us; speedup 1.0000x reference)
//
#include <hip/hip_runtime.h>
#include <hip/hip_bf16.h>

// ---------------------------------------------------------------------------
// RNNEncoder round 8 (= round 7 resubmitted; GPU acquisition timed out).
// d_out is FLOAT32 (test's "bf16" label is a baked template string; threshold
// 0.012890625 == 2% * max|ref| 0.64453125; rounds 1/2/6's absmax 1.039 is the
// bf16-pairs-read-as-f32 signature). Inputs: f32, dict order (proven round 6).
// Math unchanged (two independent structures agreed bit-exact).
// One block per (batch, dir); 256 threads; thread j owns hidden unit j.
// ---------------------------------------------------------------------------

template<int I>
__global__ __launch_bounds__(256)
void gru_fused(const float* __restrict__ x,      // [B*T][I] layer input
               const float* __restrict__ w_ih,   // [2][768][I]
               const float* __restrict__ w_hh,   // [2][768][256]
               const float* __restrict__ b_ih,   // [2][768]
               const float* __restrict__ b_hh,   // [2][768]
               float* __restrict__ out,          // [B*T][512], fwd|bwd concat
               int T) {
  const int blk = blockIdx.x;   // 0..127
  const int b   = blk & 63;     // batch
  const int d   = blk >> 6;     // direction: 0 fwd, 1 bwd
  const int j   = threadIdx.x;  // hidden unit

  // Gate rows [r | z | n] at j, j+256, j+512.
  const float* wr_i = w_ih + ((size_t)d * 768 + j      ) * I;
  const float* wz_i = w_ih + ((size_t)d * 768 + 256 + j) * I;
  const float* wn_i = w_ih + ((size_t)d * 768 + 512 + j) * I;
  const float* wr_h = w_hh + ((size_t)d * 768 + j      ) * 256;
  const float* wz_h = w_hh + ((size_t)d * 768 + 256 + j) * 256;
  const float* wn_h = w_hh + ((size_t)d * 768 + 512 + j) * 256;

  const float bir = b_ih[d * 768 + j];
  const float biz = b_ih[d * 768 + 256 + j];
  const float bin = b_ih[d * 768 + 512 + j];
  const float bhr = b_hh[d * 768 + j];
  const float bhz = b_hh[d * 768 + 256 + j];
  const float bhn = b_hh[d * 768 + 512 + j];

  __shared__ float h[256];
  h[j] = 0.0f;
  __syncthreads();

  for (int it = 0; it < T; ++it) {
    const int t = d ? (T - 1 - it) : it;
    const float* xrow = x + ((size_t)b * T + t) * I;

    // Input projection: a{r,z,n} = x_t . w_ih_gate[j] + b_ih
    float ar = bir, az = biz, an = bin;
    #pragma unroll 4
    for (int k = 0; k < I; k += 4) {
      const float4 xv = *(const float4*)&xrow[k];
      const float4 w0 = *(const float4*)&wr_i[k];
      const float4 w1 = *(const float4*)&wz_i[k];
      const float4 w2 = *(const float4*)&wn_i[k];
      ar += xv.x*w0.x + xv.y*w0.y + xv.z*w0.z + xv.w*w0.w;
      az += xv.x*w1.x + xv.y*w1.y + xv.z*w1.z + xv.w*w1.w;
      an += xv.x*w2.x + xv.y*w2.y + xv.z*w2.z + xv.w*w2.w;
    }

    // Recurrent projection: s{r,z,n} = h . w_hh_gate[j] + b_hh
    float sr = bhr, sz = bhz, sn = bhn;
    #pragma unroll 4
    for (int k = 0; k < 256; k += 4) {
      const float4 hv = *(const float4*)&h[k];
      const float4 w0 = *(const float4*)&wr_h[k];
      const float4 w1 = *(const float4*)&wz_h[k];
      const float4 w2 = *(const float4*)&wn_h[k];
      sr += hv.x*w0.x + hv.y*w0.y + hv.z*w0.z + hv.w*w0.w;
      sz += hv.x*w1.x + hv.y*w1.y + hv.z*w1.z + hv.w*w1.w;
      sn += hv.x*w2.x + hv.y*w2.y + hv.z*w2.z + hv.w*w2.w;
    }

    const float hold = h[j];
    const float r = 1.0f / (1.0f + expf(-(ar + sr)));
    const float z = 1.0f / (1.0f + expf(-(az + sz)));
    const float n = tanhf(an + r * sn);          // n = tanh(xn + r*hn)
    const float hnew = (1.0f - z) * n + z * hold;

    __syncthreads();   // all reads of h for this step done
    h[j] = hnew;
    __syncthreads();   // h ready for next step

    out[((size_t)b * T + t) * 512 + (size_t)(d * 256 + j)] = hnew;
  }
}

extern "C" void kernel_launch(void* const* d_in, const int* in_sizes, int n_in,
                              void* d_out, int out_size, void* d_ws, size_t ws_size,
                              hipStream_t stream) {
  // setup_inputs() dict order, all float32 (proven rounds 5/6).
  const float* x       = (const float*)d_in[0];
  const float* w_ih_l0 = (const float*)d_in[1];
  const float* w_hh_l0 = (const float*)d_in[2];
  const float* b_ih_l0 = (const float*)d_in[3];
  const float* b_hh_l0 = (const float*)d_in[4];
  const float* w_ih_l1 = (const float*)d_in[5];
  const float* w_hh_l1 = (const float*)d_in[6];
  const float* b_ih_l1 = (const float*)d_in[7];
  const float* b_hh_l1 = (const float*)d_in[8];
  float* out = (float*)d_out;                 // FLOAT32 output [B,T,512]

  const int T = 512;
  float* out0 = (float*)d_ws;   // [64*512][512] f32 = 64 MiB intermediate

  // Layer 0: x [B,T,128] -> intermediate [B,T,512] (fwd|bwd).
  gru_fused<128><<<128, 256, 0, stream>>>(
      x, w_ih_l0, w_hh_l0, b_ih_l0, b_hh_l0, out0, T);
  // Layer 1: intermediate -> final f32 output [B,T,512].
  gru_fused<512><<<128, 256, 0, stream>>>(
      out0, w_ih_l1, w_hh_l1, b_ih_l1, b_hh_l1, out, T);
}

// Round 9
// 20403.717 us; speedup vs baseline: 2.4413x; 2.4413x over previous
//
#include <hip/hip_runtime.h>

// ---------------------------------------------------------------------------
// RNNEncoder round 9: kill the HBM weight-refetch (9.8 GB/dispatch -> ~0.2 GB).
//   * weights pre-transposed to [K/4][1536] float4 rows -> coalesced L2 stream
//   * nontemporal loads/stores for x/out -> no L2 write-allocate pollution
//   * XCD-aware d mapping: one direction per XCD -> weight set fits 4 MiB L2
//   * NB=2 batches per block: weight register reused for 2 batches
// Block = 768 threads; thread r owns gate-row r (r<256:r, <512:z, <768:n) for
// its 2 batches. h (2x256) in LDS; gates via LDS; 3 syncs/step.
// Math identical to round 8 (f32, expf/tanhf). Output f32.
// ---------------------------------------------------------------------------

// transpose [R][K] -> [K/4][R][4]  (element (k4, r, k&3))
__global__ __launch_bounds__(256)
void wtrans(const float* __restrict__ src, float* __restrict__ dst, int R, int K) {
  const int idx = blockIdx.x * 256 + threadIdx.x;
  if (idx >= R * K) return;
  const int r = idx / K, k = idx - r * K;
  dst[((size_t)(k >> 2) * R + r) * 4 + (k & 3)] = src[idx];
}

template<int I>
__global__ __launch_bounds__(768)
void gru_layer(const float* __restrict__ x,     // [B*T][I]
               const float* __restrict__ wiT,   // [I/4][1536] float4
               const float* __restrict__ whT,   // [64][1536] float4
               const float* __restrict__ b_ih,  // [2][768]
               const float* __restrict__ b_hh,  // [2][768]
               float* __restrict__ out,         // [B*T][512], fwd|bwd concat
               int T) {
  const int bid = blockIdx.x;          // 0..63
  const int xcd = bid & 7;             // assumed round-robin XCD id
  const int d   = xcd >> 2;            // direction: XCDs 0-3 fwd, 4-7 bwd
  const int bg  = ((bid >> 3) << 2) + (xcd & 3);  // 0..31 (bijective)
  const int b0  = bg * 2;              // first of 2 batches
  const int tid = threadIdx.x;         // 0..767 = gate-row
  const int row = d * 768 + tid;       // row in transposed weight arrays

  const float bi = b_ih[row];
  const float bh = b_hh[row];

  __shared__ float xb[2][I];           // staged x rows (2 batches)
  __shared__ float hb[2][256];         // h state
  __shared__ float ga[768][2];         // x-side preactivation (incl b_ih)
  __shared__ float gs[768][2];         // h-side preactivation (incl b_hh)

  if (tid < 512) hb[tid >> 8][tid & 255] = 0.0f;
  __syncthreads();

  const float4* wi4 = (const float4*)wiT;   // [(I/4)][1536]
  const float4* wh4 = (const float4*)whT;   // [64][1536]

  for (int it = 0; it < T; ++it) {
    const int t = d ? (T - 1 - it) : it;

    // ---- stage the 2 x rows into LDS (nontemporal: read-once data) ----
    #pragma unroll
    for (int i = tid; i < 2 * I; i += 768) {
      const int bb = (i >= I);                    // 2*I <= 1024, so 0/1
      const int k  = i - bb * I;
      xb[bb][k] = __builtin_nontemporal_load(&x[((size_t)(b0 + bb) * T + t) * I + k]);
    }
    __syncthreads();

    // ---- row dot products: coalesced weight stream, LDS broadcast x/h ----
    float a0 = bi, a1 = bi, s0 = bh, s1 = bh;
    #pragma unroll 8
    for (int k4 = 0; k4 < I / 4; ++k4) {
      const float4 w = wi4[(size_t)k4 * 1536 + row];
      const float4 p = *(const float4*)&xb[0][k4 * 4];
      const float4 q = *(const float4*)&xb[1][k4 * 4];
      a0 += w.x*p.x + w.y*p.y + w.z*p.z + w.w*p.w;
      a1 += w.x*q.x + w.y*q.y + w.z*q.z + w.w*q.w;
    }
    #pragma unroll 8
    for (int k4 = 0; k4 < 64; ++k4) {
      const float4 w = wh4[(size_t)k4 * 1536 + row];
      const float4 p = *(const float4*)&hb[0][k4 * 4];
      const float4 q = *(const float4*)&hb[1][k4 * 4];
      s0 += w.x*p.x + w.y*p.y + w.z*p.z + w.w*p.w;
      s1 += w.x*q.x + w.y*q.y + w.z*q.z + w.w*q.w;
    }
    ga[tid][0] = a0; ga[tid][1] = a1;
    gs[tid][0] = s0; gs[tid][1] = s1;
    __syncthreads();

    // ---- gate math + h update: thread (j, bb) for j<256, bb<2 ----
    if (tid < 512) {
      const int j  = tid & 255;
      const int bb = tid >> 8;
      const float rr = 1.0f / (1.0f + expf(-(ga[j      ][bb] + gs[j      ][bb])));
      const float zz = 1.0f / (1.0f + expf(-(ga[j + 256][bb] + gs[j + 256][bb])));
      const float nn = tanhf(ga[j + 512][bb] + rr * gs[j + 512][bb]);
      const float hnew = (1.0f - zz) * nn + zz * hb[bb][j];
      hb[bb][j] = hnew;
      __builtin_nontemporal_store(hnew,
          &out[((size_t)(b0 + bb) * T + t) * 512 + (size_t)(d * 256 + j)]);
    }
    __syncthreads();
  }
}

extern "C" void kernel_launch(void* const* d_in, const int* in_sizes, int n_in,
                              void* d_out, int out_size, void* d_ws, size_t ws_size,
                              hipStream_t stream) {
  // setup_inputs() dict order, all float32; output float32 (proven rounds 6-8).
  const float* x       = (const float*)d_in[0];
  const float* w_ih_l0 = (const float*)d_in[1];
  const float* w_hh_l0 = (const float*)d_in[2];
  const float* b_ih_l0 = (const float*)d_in[3];
  const float* b_hh_l0 = (const float*)d_in[4];
  const float* w_ih_l1 = (const float*)d_in[5];
  const float* w_hh_l1 = (const float*)d_in[6];
  const float* b_ih_l1 = (const float*)d_in[7];
  const float* b_hh_l1 = (const float*)d_in[8];
  float* out = (float*)d_out;

  const int T = 512;

  // ws layout (f32): out0 | wiT0 | whT0 | wiT1 | whT1
  float* out0 = (float*)d_ws;                    // 64*512*512   = 16.78M
  float* wiT0 = out0 + (size_t)64 * 512 * 512;   // 1536*128
  float* whT0 = wiT0 + (size_t)1536 * 128;       // 1536*256
  float* wiT1 = whT0 + (size_t)1536 * 256;       // 1536*512
  float* whT1 = wiT1 + (size_t)1536 * 512;       // 1536*256

  // transpose weights into streaming-friendly layout (reruns every launch;
  // ws is re-poisoned before each timed call)
  wtrans<<<(1536 * 128 + 255) / 256, 256, 0, stream>>>(w_ih_l0, wiT0, 1536, 128);
  wtrans<<<(1536 * 256 + 255) / 256, 256, 0, stream>>>(w_hh_l0, whT0, 1536, 256);
  wtrans<<<(1536 * 512 + 255) / 256, 256, 0, stream>>>(w_ih_l1, wiT1, 1536, 512);
  wtrans<<<(1536 * 256 + 255) / 256, 256, 0, stream>>>(w_hh_l1, whT1, 1536, 256);

  // Layer 0: x [B,T,128] -> out0 [B,T,512]
  gru_layer<128><<<64, 768, 0, stream>>>(x, wiT0, whT0, b_ih_l0, b_hh_l0, out0, T);
  // Layer 1: out0 -> final f32 output [B,T,512]
  gru_layer<512><<<64, 768, 0, stream>>>(out0, wiT1, whT1, b_ih_l1, b_hh_l1, out, T);
}